// Round 7
// baseline (247.840 us; speedup 1.0000x reference)
//
#include <hip/hip_runtime.h>

#define F_IN 128
#define HID 64
#define FC_HID 128
#define NOUT 2
#define NGR 8
#define SLOPE 0.01f
#define SLOTS 64   // padded in-edge slots per node (avg in-degree 16)

// ---------------- zero workspace head (cnt + fc1out + ticket) ----------------
__global__ void zero_kernel(int4* __restrict__ p, int n4) {
    int i = blockIdx.x * blockDim.x + threadIdx.x;
    if (i < n4) p[i] = make_int4(0, 0, 0, 0);
}

// ---------------- edge scatter: build padded per-dst edge list ----------------
__global__ __launch_bounds__(256) void scatter_kernel(const int* __restrict__ src,
                                                      const int* __restrict__ dst,
                                                      const float* __restrict__ edge_attr,
                                                      int* __restrict__ cnt,
                                                      int2* __restrict__ slots, int E) {
    int t = blockIdx.x * blockDim.x + threadIdx.x;
    int base = t * 4;
    if (base + 3 < E) {
        int4 s4 = *(const int4*)(src + base);
        int4 d4 = *(const int4*)(dst + base);
        float4 a0 = *(const float4*)(edge_attr + (size_t)2 * base);
        float4 a1 = *(const float4*)(edge_attr + (size_t)2 * base + 4);
        int d[4] = {d4.x, d4.y, d4.z, d4.w};
        int2 rec[4];
        rec[0] = make_int2(s4.x, __float_as_int(a0.x));
        rec[1] = make_int2(s4.y, __float_as_int(a0.z));
        rec[2] = make_int2(s4.z, __float_as_int(a1.x));
        rec[3] = make_int2(s4.w, __float_as_int(a1.z));
        int pos[4];
        #pragma unroll
        for (int k = 0; k < 4; ++k) pos[k] = atomicAdd(&cnt[d[k]], 1);
        #pragma unroll
        for (int k = 0; k < 4; ++k)
            if (pos[k] < SLOTS) slots[(size_t)d[k] * SLOTS + pos[k]] = rec[k];
    } else {
        for (int e = base; e < E; ++e) {
            int s = src[e], d = dst[e];
            float w = edge_attr[(size_t)2 * e];
            int pos = atomicAdd(&cnt[d], 1);
            if (pos < SLOTS) slots[(size_t)d * SLOTS + pos] = make_int2(s, __float_as_int(w));
        }
    }
}

// ---------------- dinv[d] = rsqrt(sum_w(slots[d]) + 1), wave per node ----------------
__global__ __launch_bounds__(256) void dinv_kernel(const int2* __restrict__ slots,
                                                   const int* __restrict__ cnt,
                                                   float* __restrict__ dinv, int N) {
    int d = blockIdx.x * 4 + (threadIdx.x >> 6);
    if (d >= N) return;
    int lane = threadIdx.x & 63;
    int c = cnt[d]; if (c > SLOTS) c = SLOTS;
    float w = (lane < c) ? __int_as_float(slots[(size_t)d * SLOTS + lane].y) : 0.0f;
    #pragma unroll
    for (int m = 32; m >= 1; m >>= 1)
        w += __shfl_xor(w, m, 64);
    if (lane == 0) dinv[d] = rsqrtf(w + 1.0f);
}

// ---------------- xw = x @ W1: register-tiled 4x4, 64x64 rows/cols per block ----------------
// Thread (tr = tid&15, tc = tid>>4) computes rows {tr+16i} x cols {4tc..4tc+3}.
// Per k-quad: 4 ds_read_b128 (xs) + 4 ds_read_b128 (Wl) for 64 FMAs.
#define XS_STR 140   // row stride in floats: 12*tr mod 32 spreads banks (~2-way)
__global__ __launch_bounds__(256) void gemm1_kernel(const float* __restrict__ x,
                                                    const float* __restrict__ W1,
                                                    float* __restrict__ xw, int N) {
    __shared__ float xs[64 * XS_STR];       // 35.8 KB
    __shared__ float wl[F_IN * HID];        // 32 KB

    int tid = threadIdx.x;
    int rowBase = blockIdx.x * 64;

    // stage W1 (flat copy, 8 float4 per thread)
    #pragma unroll
    for (int i = 0; i < 8; ++i) {
        int f = tid + i * 256;              // float4 index
        *(float4*)&wl[f * 4] = *(const float4*)&W1[f * 4];
    }
    // stage 64 rows of x (8 float4 per thread), padded rows
    #pragma unroll
    for (int i = 0; i < 8; ++i) {
        int f = tid + i * 256;              // float4 index over 64x128
        int r = f >> 5, q = f & 31;
        if (rowBase + r < N)
            *(float4*)&xs[r * XS_STR + q * 4] = *(const float4*)&x[(size_t)(rowBase + r) * F_IN + q * 4];
    }
    __syncthreads();

    int tr = tid & 15;
    int tc = tid >> 4;

    float4 acc0 = {0,0,0,0}, acc1 = {0,0,0,0}, acc2 = {0,0,0,0}, acc3 = {0,0,0,0};
    #pragma unroll
    for (int k = 0; k < F_IN; k += 4) {
        float4 a0 = *(const float4*)&xs[(tr     ) * XS_STR + k];
        float4 a1 = *(const float4*)&xs[(tr + 16) * XS_STR + k];
        float4 a2 = *(const float4*)&xs[(tr + 32) * XS_STR + k];
        float4 a3 = *(const float4*)&xs[(tr + 48) * XS_STR + k];
        float4 w0 = *(const float4*)&wl[(k    ) * HID + tc * 4];
        float4 w1 = *(const float4*)&wl[(k + 1) * HID + tc * 4];
        float4 w2 = *(const float4*)&wl[(k + 2) * HID + tc * 4];
        float4 w3 = *(const float4*)&wl[(k + 3) * HID + tc * 4];
        acc0.x += a0.x*w0.x + a0.y*w1.x + a0.z*w2.x + a0.w*w3.x;
        acc0.y += a0.x*w0.y + a0.y*w1.y + a0.z*w2.y + a0.w*w3.y;
        acc0.z += a0.x*w0.z + a0.y*w1.z + a0.z*w2.z + a0.w*w3.z;
        acc0.w += a0.x*w0.w + a0.y*w1.w + a0.z*w2.w + a0.w*w3.w;
        acc1.x += a1.x*w0.x + a1.y*w1.x + a1.z*w2.x + a1.w*w3.x;
        acc1.y += a1.x*w0.y + a1.y*w1.y + a1.z*w2.y + a1.w*w3.y;
        acc1.z += a1.x*w0.z + a1.y*w1.z + a1.z*w2.z + a1.w*w3.z;
        acc1.w += a1.x*w0.w + a1.y*w1.w + a1.z*w2.w + a1.w*w3.w;
        acc2.x += a2.x*w0.x + a2.y*w1.x + a2.z*w2.x + a2.w*w3.x;
        acc2.y += a2.x*w0.y + a2.y*w1.y + a2.z*w2.y + a2.w*w3.y;
        acc2.z += a2.x*w0.z + a2.y*w1.z + a2.z*w2.z + a2.w*w3.z;
        acc2.w += a2.x*w0.w + a2.y*w1.w + a2.z*w2.w + a2.w*w3.w;
        acc3.x += a3.x*w0.x + a3.y*w1.x + a3.z*w2.x + a3.w*w3.x;
        acc3.y += a3.x*w0.y + a3.y*w1.y + a3.z*w2.y + a3.w*w3.y;
        acc3.z += a3.x*w0.z + a3.y*w1.z + a3.z*w2.z + a3.w*w3.z;
        acc3.w += a3.x*w0.w + a3.y*w1.w + a3.z*w2.w + a3.w*w3.w;
    }

    int row0 = rowBase + tr;
    if (row0      < N) *(float4*)&xw[(size_t)(row0     ) * HID + tc * 4] = acc0;
    if (row0 + 16 < N) *(float4*)&xw[(size_t)(row0 + 16) * HID + tc * 4] = acc1;
    if (row0 + 32 < N) *(float4*)&xw[(size_t)(row0 + 32) * HID + tc * 4] = acc2;
    if (row0 + 48 < N) *(float4*)&xw[(size_t)(row0 + 48) * HID + tc * 4] = acc3;
}

// ---------------- conv1 gather (fused: agg + self + bias + leaky + @W2 reduce) ----------------
__global__ __launch_bounds__(256) void gather1_kernel(const int2* __restrict__ slots,
                                                      const int* __restrict__ cnt,
                                                      const float* __restrict__ dinv,
                                                      const float* __restrict__ xw,
                                                      const float* __restrict__ b1,
                                                      const float* __restrict__ W2,
                                                      float* __restrict__ hw, int N) {
    int d = blockIdx.x * 4 + (threadIdx.x >> 6);
    if (d >= N) return;
    int lane = threadIdx.x & 63;
    int c = cnt[d]; if (c > SLOTS) c = SLOTS;

    int   sidx = 0;
    float nrm  = 0.0f;
    if (lane < c) {
        int2 sw = slots[(size_t)d * SLOTS + lane];
        sidx = sw.x;
        nrm  = dinv[sw.x] * __int_as_float(sw.y);
    }
    float di    = dinv[d];
    float self  = xw[(size_t)d * HID + lane];

    float acc0 = 0.0f, acc1 = 0.0f, acc2 = 0.0f, acc3 = 0.0f;
    int i = 0;
    for (; i + 7 < c; i += 8) {
        int   s0 = __shfl(sidx, i,     64); float n0 = __shfl(nrm, i,     64);
        int   s1 = __shfl(sidx, i + 1, 64); float n1 = __shfl(nrm, i + 1, 64);
        int   s2 = __shfl(sidx, i + 2, 64); float n2 = __shfl(nrm, i + 2, 64);
        int   s3 = __shfl(sidx, i + 3, 64); float n3 = __shfl(nrm, i + 3, 64);
        int   s4 = __shfl(sidx, i + 4, 64); float n4 = __shfl(nrm, i + 4, 64);
        int   s5 = __shfl(sidx, i + 5, 64); float n5 = __shfl(nrm, i + 5, 64);
        int   s6 = __shfl(sidx, i + 6, 64); float n6 = __shfl(nrm, i + 6, 64);
        int   s7 = __shfl(sidx, i + 7, 64); float n7 = __shfl(nrm, i + 7, 64);
        float v0 = xw[(size_t)s0 * HID + lane];
        float v1 = xw[(size_t)s1 * HID + lane];
        float v2 = xw[(size_t)s2 * HID + lane];
        float v3 = xw[(size_t)s3 * HID + lane];
        float v4 = xw[(size_t)s4 * HID + lane];
        float v5 = xw[(size_t)s5 * HID + lane];
        float v6 = xw[(size_t)s6 * HID + lane];
        float v7 = xw[(size_t)s7 * HID + lane];
        acc0 += v0 * n0; acc1 += v1 * n1; acc2 += v2 * n2; acc3 += v3 * n3;
        acc0 += v4 * n4; acc1 += v5 * n5; acc2 += v6 * n6; acc3 += v7 * n7;
    }
    for (; i + 3 < c; i += 4) {
        int   s0 = __shfl(sidx, i,     64); float n0 = __shfl(nrm, i,     64);
        int   s1 = __shfl(sidx, i + 1, 64); float n1 = __shfl(nrm, i + 1, 64);
        int   s2 = __shfl(sidx, i + 2, 64); float n2 = __shfl(nrm, i + 2, 64);
        int   s3 = __shfl(sidx, i + 3, 64); float n3 = __shfl(nrm, i + 3, 64);
        acc0 += xw[(size_t)s0 * HID + lane] * n0;
        acc1 += xw[(size_t)s1 * HID + lane] * n1;
        acc2 += xw[(size_t)s2 * HID + lane] * n2;
        acc3 += xw[(size_t)s3 * HID + lane] * n3;
    }
    for (; i < c; ++i) {
        int s = __shfl(sidx, i, 64); float n = __shfl(nrm, i, 64);
        acc0 += xw[(size_t)s * HID + lane] * n;
    }
    float acc = (acc0 + acc1) + (acc2 + acc3);

    float v = acc * di + self * di * di + b1[lane];
    v = (v >= 0.0f) ? v : SLOPE * v;
    float p = v * W2[lane];
    #pragma unroll
    for (int m = 32; m >= 1; m >>= 1)
        p += __shfl_xor(p, m, 64);
    if (lane == 0) hw[d] = p;
}

// ---------------- conv2 gather (fused h2): one wave per dst node, lane = edge slot ----------------
__global__ __launch_bounds__(256) void gather2_kernel(const int2* __restrict__ slots,
                                                      const int* __restrict__ cnt,
                                                      const float* __restrict__ dinv,
                                                      const float* __restrict__ hw,
                                                      const float* __restrict__ b2,
                                                      float* __restrict__ h2, int N) {
    int d = blockIdx.x * 4 + (threadIdx.x >> 6);
    if (d >= N) return;
    int lane = threadIdx.x & 63;
    int c = cnt[d]; if (c > SLOTS) c = SLOTS;
    float p = 0.0f;
    if (lane < c) {
        int2 sw = slots[(size_t)d * SLOTS + lane];
        int s = sw.x;
        float w = __int_as_float(sw.y);
        p = hw[s] * dinv[s] * w;
    }
    #pragma unroll
    for (int m = 32; m >= 1; m >>= 1)
        p += __shfl_xor(p, m, 64);
    if (lane == 0) {
        float di = dinv[d];
        float v = p * di + hw[d] * di * di + b2[0];
        h2[d] = (v >= 0.0f) ? v : SLOPE * v;
    }
}

// ---------------- FC1 split-K partial + last-block finalize (fc2 + softmax) ----------------
#define ROWS_PB 16
__global__ __launch_bounds__(128) void fcpart_kernel(const float* __restrict__ h2,
                                                     const float* __restrict__ fc1_W,
                                                     float* __restrict__ fc1_out,
                                                     int* __restrict__ ticket,
                                                     const float* __restrict__ fc1_b,
                                                     const float* __restrict__ fc2_W,
                                                     const float* __restrict__ fc2_b,
                                                     float* __restrict__ out,
                                                     int nodesPerG) {
    int j = threadIdx.x;
    int row0 = blockIdx.x * ROWS_PB;
    __shared__ float hs[NGR][ROWS_PB];
    for (int idx = threadIdx.x; idx < NGR * ROWS_PB; idx += 128) {
        int g = idx / ROWS_PB, r = idx % ROWS_PB;
        hs[g][r] = h2[(size_t)g * nodesPerG + row0 + r];
    }
    __syncthreads();
    float acc[NGR];
    #pragma unroll
    for (int g = 0; g < NGR; ++g) acc[g] = 0.0f;
    #pragma unroll
    for (int r = 0; r < ROWS_PB; ++r) {
        float wv = fc1_W[(size_t)(row0 + r) * FC_HID + j];
        #pragma unroll
        for (int g = 0; g < NGR; ++g) acc[g] += hs[g][r] * wv;
    }
    #pragma unroll
    for (int g = 0; g < NGR; ++g) atomicAdd(&fc1_out[g * FC_HID + j], acc[g]);

    // last-block finalize
    __threadfence();
    __shared__ int lastFlag;
    if (j == 0) lastFlag = (atomicAdd(ticket, 1) == (int)gridDim.x - 1);
    __syncthreads();
    if (!lastFlag) return;
    __threadfence();

    __shared__ float hid[NGR][FC_HID];
    __shared__ float outs[NGR * NOUT];
    #pragma unroll
    for (int g = 0; g < NGR; ++g) {
        float v = atomicAdd(&fc1_out[g * FC_HID + j], 0.0f) + fc1_b[j];  // coherent load
        hid[g][j] = (v >= 0.0f) ? v : SLOPE * v;
    }
    __syncthreads();
    if (j < NGR * NOUT) {
        int g = j >> 1, o = j & 1;
        float a = fc2_b[o];
        #pragma unroll
        for (int k = 0; k < FC_HID; ++k)
            a += hid[g][k] * fc2_W[(size_t)k * NOUT + o];
        outs[j] = a;
    }
    __syncthreads();
    if (j < NGR) {
        float o0 = outs[j * 2], o1 = outs[j * 2 + 1];
        float m = fmaxf(o0, o1);
        float e0 = __expf(o0 - m), e1 = __expf(o1 - m);
        float s = e0 + e1;
        out[(size_t)j * NOUT + 0] = e0 / s;
        out[(size_t)j * NOUT + 1] = e1 / s;
    }
}

extern "C" void kernel_launch(void* const* d_in, const int* in_sizes, int n_in,
                              void* d_out, int out_size, void* d_ws, size_t ws_size,
                              hipStream_t stream) {
    const float* x          = (const float*)d_in[0];
    const int*   edge_index = (const int*)d_in[1];
    const float* edge_attr  = (const float*)d_in[2];
    const float* W1         = (const float*)d_in[3];
    const float* b1         = (const float*)d_in[4];
    const float* W2         = (const float*)d_in[5];
    const float* b2         = (const float*)d_in[6];
    const float* fc1_W      = (const float*)d_in[7];
    const float* fc1_b      = (const float*)d_in[8];
    const float* fc2_W      = (const float*)d_in[9];
    const float* fc2_b      = (const float*)d_in[10];
    float* out = (float*)d_out;

    int N = in_sizes[0] / F_IN;
    int E = in_sizes[1] / 2;
    int nodesPerG = in_sizes[7] / FC_HID;

    const int* src = edge_index;
    const int* dst = edge_index + E;

    // workspace layout: zeroed region first (cnt + fc1out + ticket)
    char* wsb = (char*)d_ws;
    int*   cnt    = (int*)wsb;                                   // N ints
    float* fc1out = (float*)(wsb + (size_t)N * 4);               // NGR*FC_HID floats
    int*   ticket = (int*)(wsb + (size_t)N * 4 + NGR * FC_HID * 4);  // 1 int (pad to 16)
    size_t zeroBytes = (size_t)N * 4 + (size_t)NGR * FC_HID * 4 + 16;
    int2*  slots  = (int2*)(wsb + zeroBytes);                    // N*SLOTS int2 (16 MB)
    float* xw     = (float*)(wsb + zeroBytes + (size_t)N * SLOTS * 8);  // N*HID
    float* dinv   = xw + (size_t)N * HID;                        // N
    float* hw     = dinv + N;                                    // N
    float* h2     = hw + N;                                      // N

    int n4 = (int)(zeroBytes / 16);
    zero_kernel<<<(n4 + 255) / 256, 256, 0, stream>>>((int4*)d_ws, n4);

    scatter_kernel<<<(E / 4 + 255) / 256, 256, 0, stream>>>(src, dst, edge_attr, cnt, slots, E);
    dinv_kernel<<<(N + 3) / 4, 256, 0, stream>>>(slots, cnt, dinv, N);
    gemm1_kernel<<<(N + 63) / 64, 256, 0, stream>>>(x, W1, xw, N);
    gather1_kernel<<<(N + 3) / 4, 256, 0, stream>>>(slots, cnt, dinv, xw, b1, W2, hw, N);
    gather2_kernel<<<(N + 3) / 4, 256, 0, stream>>>(slots, cnt, dinv, hw, b2, h2, N);
    fcpart_kernel<<<nodesPerG / ROWS_PB, 128, 0, stream>>>(h2, fc1_W, fc1out, ticket,
                                                           fc1_b, fc2_W, fc2_b, out, nodesPerG);
}

// Round 8
// 106.104 us; speedup vs baseline: 2.3358x; 2.3358x over previous
//
#include <hip/hip_runtime.h>

#define F_IN 128
#define HID 64
#define FC_HID 128
#define NOUT 2
#define NGR 8
#define SLOPE 0.01f
#define SLOTS 64   // padded in-edge slots per node (avg in-degree 16)

// ---------------- zero workspace head (cnt + fc1out + ticket) ----------------
__global__ void zero_kernel(int4* __restrict__ p, int n4) {
    int i = blockIdx.x * blockDim.x + threadIdx.x;
    if (i < n4) p[i] = make_int4(0, 0, 0, 0);
}

// ---------------- edge scatter: build padded per-dst edge list ----------------
__global__ __launch_bounds__(256) void scatter_kernel(const int* __restrict__ src,
                                                      const int* __restrict__ dst,
                                                      const float* __restrict__ edge_attr,
                                                      int* __restrict__ cnt,
                                                      int2* __restrict__ slots, int E) {
    int t = blockIdx.x * blockDim.x + threadIdx.x;
    int base = t * 4;
    if (base + 3 < E) {
        int4 s4 = *(const int4*)(src + base);
        int4 d4 = *(const int4*)(dst + base);
        float4 a0 = *(const float4*)(edge_attr + (size_t)2 * base);
        float4 a1 = *(const float4*)(edge_attr + (size_t)2 * base + 4);
        int d[4] = {d4.x, d4.y, d4.z, d4.w};
        int2 rec[4];
        rec[0] = make_int2(s4.x, __float_as_int(a0.x));
        rec[1] = make_int2(s4.y, __float_as_int(a0.z));
        rec[2] = make_int2(s4.z, __float_as_int(a1.x));
        rec[3] = make_int2(s4.w, __float_as_int(a1.z));
        int pos[4];
        #pragma unroll
        for (int k = 0; k < 4; ++k) pos[k] = atomicAdd(&cnt[d[k]], 1);
        #pragma unroll
        for (int k = 0; k < 4; ++k)
            if (pos[k] < SLOTS) slots[(size_t)d[k] * SLOTS + pos[k]] = rec[k];
    } else {
        for (int e = base; e < E; ++e) {
            int s = src[e], d = dst[e];
            float w = edge_attr[(size_t)2 * e];
            int pos = atomicAdd(&cnt[d], 1);
            if (pos < SLOTS) slots[(size_t)d * SLOTS + pos] = make_int2(s, __float_as_int(w));
        }
    }
}

// ---------------- dinv[d] = rsqrt(sum_w(slots[d]) + 1), wave per node ----------------
__global__ __launch_bounds__(256) void dinv_kernel(const int2* __restrict__ slots,
                                                   const int* __restrict__ cnt,
                                                   float* __restrict__ dinv, int N) {
    int d = blockIdx.x * 4 + (threadIdx.x >> 6);
    if (d >= N) return;
    int lane = threadIdx.x & 63;
    int c = cnt[d]; if (c > SLOTS) c = SLOTS;
    float w = (lane < c) ? __int_as_float(slots[(size_t)d * SLOTS + lane].y) : 0.0f;
    #pragma unroll
    for (int m = 32; m >= 1; m >>= 1)
        w += __shfl_xor(w, m, 64);
    if (lane == 0) dinv[d] = rsqrtf(w + 1.0f);
}

// ---------------- xw = x @ W1: register-tiled 4x4, 64 rows x 64 cols per block ----------------
// Thread (tr = tid&15, tc = tid>>4) computes rows {tr+16i} x cols {4tc..4tc+3}.
// k-loop unroll CAPPED at 2 — full unroll spilled to scratch (R7: 293MB scratch writes).
#define XS_STR 140   // row stride in floats: 12*tr mod 32 spreads start banks (2-way = free)
__global__ __launch_bounds__(256) void gemm1_kernel(const float* __restrict__ x,
                                                    const float* __restrict__ W1,
                                                    float* __restrict__ xw, int N) {
    __shared__ float xs[64 * XS_STR];       // 35.8 KB
    __shared__ float wl[F_IN * HID];        // 32 KB

    int tid = threadIdx.x;
    int rowBase = blockIdx.x * 64;

    #pragma unroll
    for (int i = 0; i < 8; ++i) {
        int f = tid + i * 256;              // float4 index over W1 (128*64/4 = 2048)
        *(float4*)&wl[f * 4] = *(const float4*)&W1[f * 4];
    }
    #pragma unroll
    for (int i = 0; i < 8; ++i) {
        int f = tid + i * 256;              // float4 index over 64x128
        int r = f >> 5, q = f & 31;
        if (rowBase + r < N)
            *(float4*)&xs[r * XS_STR + q * 4] = *(const float4*)&x[(size_t)(rowBase + r) * F_IN + q * 4];
    }
    __syncthreads();

    int tr = tid & 15;
    int tc = tid >> 4;

    float4 acc0 = {0,0,0,0}, acc1 = {0,0,0,0}, acc2 = {0,0,0,0}, acc3 = {0,0,0,0};
    #pragma unroll 2
    for (int k = 0; k < F_IN; k += 4) {
        float4 a0 = *(const float4*)&xs[(tr     ) * XS_STR + k];
        float4 a1 = *(const float4*)&xs[(tr + 16) * XS_STR + k];
        float4 a2 = *(const float4*)&xs[(tr + 32) * XS_STR + k];
        float4 a3 = *(const float4*)&xs[(tr + 48) * XS_STR + k];
        float4 w0 = *(const float4*)&wl[(k    ) * HID + tc * 4];
        float4 w1 = *(const float4*)&wl[(k + 1) * HID + tc * 4];
        float4 w2 = *(const float4*)&wl[(k + 2) * HID + tc * 4];
        float4 w3 = *(const float4*)&wl[(k + 3) * HID + tc * 4];
        acc0.x += a0.x*w0.x + a0.y*w1.x + a0.z*w2.x + a0.w*w3.x;
        acc0.y += a0.x*w0.y + a0.y*w1.y + a0.z*w2.y + a0.w*w3.y;
        acc0.z += a0.x*w0.z + a0.y*w1.z + a0.z*w2.z + a0.w*w3.z;
        acc0.w += a0.x*w0.w + a0.y*w1.w + a0.z*w2.w + a0.w*w3.w;
        acc1.x += a1.x*w0.x + a1.y*w1.x + a1.z*w2.x + a1.w*w3.x;
        acc1.y += a1.x*w0.y + a1.y*w1.y + a1.z*w2.y + a1.w*w3.y;
        acc1.z += a1.x*w0.z + a1.y*w1.z + a1.z*w2.z + a1.w*w3.z;
        acc1.w += a1.x*w0.w + a1.y*w1.w + a1.z*w2.w + a1.w*w3.w;
        acc2.x += a2.x*w0.x + a2.y*w1.x + a2.z*w2.x + a2.w*w3.x;
        acc2.y += a2.x*w0.y + a2.y*w1.y + a2.z*w2.y + a2.w*w3.y;
        acc2.z += a2.x*w0.z + a2.y*w1.z + a2.z*w2.z + a2.w*w3.z;
        acc2.w += a2.x*w0.w + a2.y*w1.w + a2.z*w2.w + a2.w*w3.w;
        acc3.x += a3.x*w0.x + a3.y*w1.x + a3.z*w2.x + a3.w*w3.x;
        acc3.y += a3.x*w0.y + a3.y*w1.y + a3.z*w2.y + a3.w*w3.y;
        acc3.z += a3.x*w0.z + a3.y*w1.z + a3.z*w2.z + a3.w*w3.z;
        acc3.w += a3.x*w0.w + a3.y*w1.w + a3.z*w2.w + a3.w*w3.w;
    }

    int row0 = rowBase + tr;
    if (row0      < N) *(float4*)&xw[(size_t)(row0     ) * HID + tc * 4] = acc0;
    if (row0 + 16 < N) *(float4*)&xw[(size_t)(row0 + 16) * HID + tc * 4] = acc1;
    if (row0 + 32 < N) *(float4*)&xw[(size_t)(row0 + 32) * HID + tc * 4] = acc2;
    if (row0 + 48 < N) *(float4*)&xw[(size_t)(row0 + 48) * HID + tc * 4] = acc3;
}

// ---------------- conv1 gather (fused: agg + self + bias + leaky + @W2 reduce) ----------------
__global__ __launch_bounds__(256) void gather1_kernel(const int2* __restrict__ slots,
                                                      const int* __restrict__ cnt,
                                                      const float* __restrict__ dinv,
                                                      const float* __restrict__ xw,
                                                      const float* __restrict__ b1,
                                                      const float* __restrict__ W2,
                                                      float* __restrict__ hw, int N) {
    int d = blockIdx.x * 4 + (threadIdx.x >> 6);
    if (d >= N) return;
    int lane = threadIdx.x & 63;
    int c = cnt[d]; if (c > SLOTS) c = SLOTS;

    int   sidx = 0;
    float nrm  = 0.0f;
    if (lane < c) {
        int2 sw = slots[(size_t)d * SLOTS + lane];
        sidx = sw.x;
        nrm  = dinv[sw.x] * __int_as_float(sw.y);
    }
    float di    = dinv[d];
    float self  = xw[(size_t)d * HID + lane];

    float acc0 = 0.0f, acc1 = 0.0f, acc2 = 0.0f, acc3 = 0.0f;
    int i = 0;
    for (; i + 7 < c; i += 8) {
        int   s0 = __shfl(sidx, i,     64); float n0 = __shfl(nrm, i,     64);
        int   s1 = __shfl(sidx, i + 1, 64); float n1 = __shfl(nrm, i + 1, 64);
        int   s2 = __shfl(sidx, i + 2, 64); float n2 = __shfl(nrm, i + 2, 64);
        int   s3 = __shfl(sidx, i + 3, 64); float n3 = __shfl(nrm, i + 3, 64);
        int   s4 = __shfl(sidx, i + 4, 64); float n4 = __shfl(nrm, i + 4, 64);
        int   s5 = __shfl(sidx, i + 5, 64); float n5 = __shfl(nrm, i + 5, 64);
        int   s6 = __shfl(sidx, i + 6, 64); float n6 = __shfl(nrm, i + 6, 64);
        int   s7 = __shfl(sidx, i + 7, 64); float n7 = __shfl(nrm, i + 7, 64);
        float v0 = xw[(size_t)s0 * HID + lane];
        float v1 = xw[(size_t)s1 * HID + lane];
        float v2 = xw[(size_t)s2 * HID + lane];
        float v3 = xw[(size_t)s3 * HID + lane];
        float v4 = xw[(size_t)s4 * HID + lane];
        float v5 = xw[(size_t)s5 * HID + lane];
        float v6 = xw[(size_t)s6 * HID + lane];
        float v7 = xw[(size_t)s7 * HID + lane];
        acc0 += v0 * n0; acc1 += v1 * n1; acc2 += v2 * n2; acc3 += v3 * n3;
        acc0 += v4 * n4; acc1 += v5 * n5; acc2 += v6 * n6; acc3 += v7 * n7;
    }
    for (; i + 3 < c; i += 4) {
        int   s0 = __shfl(sidx, i,     64); float n0 = __shfl(nrm, i,     64);
        int   s1 = __shfl(sidx, i + 1, 64); float n1 = __shfl(nrm, i + 1, 64);
        int   s2 = __shfl(sidx, i + 2, 64); float n2 = __shfl(nrm, i + 2, 64);
        int   s3 = __shfl(sidx, i + 3, 64); float n3 = __shfl(nrm, i + 3, 64);
        acc0 += xw[(size_t)s0 * HID + lane] * n0;
        acc1 += xw[(size_t)s1 * HID + lane] * n1;
        acc2 += xw[(size_t)s2 * HID + lane] * n2;
        acc3 += xw[(size_t)s3 * HID + lane] * n3;
    }
    for (; i < c; ++i) {
        int s = __shfl(sidx, i, 64); float n = __shfl(nrm, i, 64);
        acc0 += xw[(size_t)s * HID + lane] * n;
    }
    float acc = (acc0 + acc1) + (acc2 + acc3);

    float v = acc * di + self * di * di + b1[lane];
    v = (v >= 0.0f) ? v : SLOPE * v;
    float p = v * W2[lane];
    #pragma unroll
    for (int m = 32; m >= 1; m >>= 1)
        p += __shfl_xor(p, m, 64);
    if (lane == 0) hw[d] = p;
}

// ---------------- conv2 gather (fused h2): one wave per dst node, lane = edge slot ----------------
__global__ __launch_bounds__(256) void gather2_kernel(const int2* __restrict__ slots,
                                                      const int* __restrict__ cnt,
                                                      const float* __restrict__ dinv,
                                                      const float* __restrict__ hw,
                                                      const float* __restrict__ b2,
                                                      float* __restrict__ h2, int N) {
    int d = blockIdx.x * 4 + (threadIdx.x >> 6);
    if (d >= N) return;
    int lane = threadIdx.x & 63;
    int c = cnt[d]; if (c > SLOTS) c = SLOTS;
    float p = 0.0f;
    if (lane < c) {
        int2 sw = slots[(size_t)d * SLOTS + lane];
        int s = sw.x;
        float w = __int_as_float(sw.y);
        p = hw[s] * dinv[s] * w;
    }
    #pragma unroll
    for (int m = 32; m >= 1; m >>= 1)
        p += __shfl_xor(p, m, 64);
    if (lane == 0) {
        float di = dinv[d];
        float v = p * di + hw[d] * di * di + b2[0];
        h2[d] = (v >= 0.0f) ? v : SLOPE * v;
    }
}

// ---------------- FC1 split-K partial + last-block finalize (fc2 + softmax) ----------------
#define ROWS_PB 16
__global__ __launch_bounds__(128) void fcpart_kernel(const float* __restrict__ h2,
                                                     const float* __restrict__ fc1_W,
                                                     float* __restrict__ fc1_out,
                                                     int* __restrict__ ticket,
                                                     const float* __restrict__ fc1_b,
                                                     const float* __restrict__ fc2_W,
                                                     const float* __restrict__ fc2_b,
                                                     float* __restrict__ out,
                                                     int nodesPerG) {
    int j = threadIdx.x;
    int row0 = blockIdx.x * ROWS_PB;
    __shared__ float hs[NGR][ROWS_PB];
    for (int idx = threadIdx.x; idx < NGR * ROWS_PB; idx += 128) {
        int g = idx / ROWS_PB, r = idx % ROWS_PB;
        hs[g][r] = h2[(size_t)g * nodesPerG + row0 + r];
    }
    __syncthreads();
    float acc[NGR];
    #pragma unroll
    for (int g = 0; g < NGR; ++g) acc[g] = 0.0f;
    #pragma unroll
    for (int r = 0; r < ROWS_PB; ++r) {
        float wv = fc1_W[(size_t)(row0 + r) * FC_HID + j];
        #pragma unroll
        for (int g = 0; g < NGR; ++g) acc[g] += hs[g][r] * wv;
    }
    #pragma unroll
    for (int g = 0; g < NGR; ++g) atomicAdd(&fc1_out[g * FC_HID + j], acc[g]);

    // last-block finalize
    __threadfence();
    __shared__ int lastFlag;
    if (j == 0) lastFlag = (atomicAdd(ticket, 1) == (int)gridDim.x - 1);
    __syncthreads();
    if (!lastFlag) return;
    __threadfence();

    __shared__ float hid[NGR][FC_HID];
    __shared__ float outs[NGR * NOUT];
    #pragma unroll
    for (int g = 0; g < NGR; ++g) {
        float v = atomicAdd(&fc1_out[g * FC_HID + j], 0.0f) + fc1_b[j];  // coherent load
        hid[g][j] = (v >= 0.0f) ? v : SLOPE * v;
    }
    __syncthreads();
    if (j < NGR * NOUT) {
        int g = j >> 1, o = j & 1;
        float a = fc2_b[o];
        #pragma unroll
        for (int k = 0; k < FC_HID; ++k)
            a += hid[g][k] * fc2_W[(size_t)k * NOUT + o];
        outs[j] = a;
    }
    __syncthreads();
    if (j < NGR) {
        float o0 = outs[j * 2], o1 = outs[j * 2 + 1];
        float m = fmaxf(o0, o1);
        float e0 = __expf(o0 - m), e1 = __expf(o1 - m);
        float s = e0 + e1;
        out[(size_t)j * NOUT + 0] = e0 / s;
        out[(size_t)j * NOUT + 1] = e1 / s;
    }
}

extern "C" void kernel_launch(void* const* d_in, const int* in_sizes, int n_in,
                              void* d_out, int out_size, void* d_ws, size_t ws_size,
                              hipStream_t stream) {
    const float* x          = (const float*)d_in[0];
    const int*   edge_index = (const int*)d_in[1];
    const float* edge_attr  = (const float*)d_in[2];
    const float* W1         = (const float*)d_in[3];
    const float* b1         = (const float*)d_in[4];
    const float* W2         = (const float*)d_in[5];
    const float* b2         = (const float*)d_in[6];
    const float* fc1_W      = (const float*)d_in[7];
    const float* fc1_b      = (const float*)d_in[8];
    const float* fc2_W      = (const float*)d_in[9];
    const float* fc2_b      = (const float*)d_in[10];
    float* out = (float*)d_out;

    int N = in_sizes[0] / F_IN;
    int E = in_sizes[1] / 2;
    int nodesPerG = in_sizes[7] / FC_HID;

    const int* src = edge_index;
    const int* dst = edge_index + E;

    // workspace layout: zeroed region first (cnt + fc1out + ticket)
    char* wsb = (char*)d_ws;
    int*   cnt    = (int*)wsb;                                   // N ints
    float* fc1out = (float*)(wsb + (size_t)N * 4);               // NGR*FC_HID floats
    int*   ticket = (int*)(wsb + (size_t)N * 4 + NGR * FC_HID * 4);  // 1 int (pad to 16)
    size_t zeroBytes = (size_t)N * 4 + (size_t)NGR * FC_HID * 4 + 16;
    int2*  slots  = (int2*)(wsb + zeroBytes);                    // N*SLOTS int2 (16 MB)
    float* xw     = (float*)(wsb + zeroBytes + (size_t)N * SLOTS * 8);  // N*HID
    float* dinv   = xw + (size_t)N * HID;                        // N
    float* hw     = dinv + N;                                    // N
    float* h2     = hw + N;                                      // N

    int n4 = (int)(zeroBytes / 16);
    zero_kernel<<<(n4 + 255) / 256, 256, 0, stream>>>((int4*)d_ws, n4);

    scatter_kernel<<<(E / 4 + 255) / 256, 256, 0, stream>>>(src, dst, edge_attr, cnt, slots, E);
    dinv_kernel<<<(N + 3) / 4, 256, 0, stream>>>(slots, cnt, dinv, N);
    gemm1_kernel<<<(N + 63) / 64, 256, 0, stream>>>(x, W1, xw, N);
    gather1_kernel<<<(N + 3) / 4, 256, 0, stream>>>(slots, cnt, dinv, xw, b1, W2, hw, N);
    gather2_kernel<<<(N + 3) / 4, 256, 0, stream>>>(slots, cnt, dinv, hw, b2, h2, N);
    fcpart_kernel<<<nodesPerG / ROWS_PB, 128, 0, stream>>>(h2, fc1_W, fc1out, ticket,
                                                           fc1_b, fc2_W, fc2_b, out, nodesPerG);
}

// Round 9
// 104.494 us; speedup vs baseline: 2.3718x; 1.0154x over previous
//
#include <hip/hip_runtime.h>

#define F_IN 128
#define HID 64
#define FC_HID 128
#define NOUT 2
#define NGR 8
#define SLOPE 0.01f
#define SLOTS 64     // padded in-edge slots per node (avg in-degree 16)
#define EPT 8        // edges per thread in scatter role

// ---------------- zero workspace head (cnt + fc1out + ticket) ----------------
__global__ void zero_kernel(int4* __restrict__ p, int n4) {
    int i = blockIdx.x * blockDim.x + threadIdx.x;
    if (i < n4) p[i] = make_int4(0, 0, 0, 0);
}

// ---------------- fused: scatter (blocks < scatB) ∥ gemm1 32-row (rest) ----------------
// Scatter: 8 edges/thread, 1 atomic/edge, batched for ILP.
// Gemm: xw = x @ W1, register-tiled 2x4 per thread, 32 rows x 64 cols per block.
// LDS = 17.9 + 32 = 50 KB -> 3 blocks/CU.
#define XS_STR 140   // row stride: 12*tr mod 32 spreads start banks (2-way = free)
__global__ __launch_bounds__(256) void fused_sg_kernel(const int* __restrict__ src,
                                                       const int* __restrict__ dst,
                                                       const float* __restrict__ edge_attr,
                                                       int* __restrict__ cnt,
                                                       int2* __restrict__ slots, int E,
                                                       const float* __restrict__ x,
                                                       const float* __restrict__ W1,
                                                       float* __restrict__ xw, int N,
                                                       int scatB) {
    __shared__ float xs[32 * XS_STR];       // 17.9 KB
    __shared__ float wl[F_IN * HID];        // 32 KB
    int tid = threadIdx.x;

    if ((int)blockIdx.x < scatB) {
        // ---------------- scatter role ----------------
        int t = blockIdx.x * 256 + tid;
        int base = t * EPT;
        if (base + EPT - 1 < E) {
            int4 sa = *(const int4*)(src + base);
            int4 sb = *(const int4*)(src + base + 4);
            int4 da = *(const int4*)(dst + base);
            int4 db = *(const int4*)(dst + base + 4);
            float4 a0 = *(const float4*)(edge_attr + (size_t)2 * base);
            float4 a1 = *(const float4*)(edge_attr + (size_t)2 * base + 4);
            float4 a2 = *(const float4*)(edge_attr + (size_t)2 * base + 8);
            float4 a3 = *(const float4*)(edge_attr + (size_t)2 * base + 12);
            int d[EPT] = {da.x, da.y, da.z, da.w, db.x, db.y, db.z, db.w};
            int2 rec[EPT];
            rec[0] = make_int2(sa.x, __float_as_int(a0.x));
            rec[1] = make_int2(sa.y, __float_as_int(a0.z));
            rec[2] = make_int2(sa.z, __float_as_int(a1.x));
            rec[3] = make_int2(sa.w, __float_as_int(a1.z));
            rec[4] = make_int2(sb.x, __float_as_int(a2.x));
            rec[5] = make_int2(sb.y, __float_as_int(a2.z));
            rec[6] = make_int2(sb.z, __float_as_int(a3.x));
            rec[7] = make_int2(sb.w, __float_as_int(a3.z));
            int pos[EPT];
            #pragma unroll
            for (int k = 0; k < EPT; ++k) pos[k] = atomicAdd(&cnt[d[k]], 1);
            #pragma unroll
            for (int k = 0; k < EPT; ++k)
                if (pos[k] < SLOTS) slots[(size_t)d[k] * SLOTS + pos[k]] = rec[k];
        } else {
            for (int e = base; e < E; ++e) {
                int s = src[e], dd = dst[e];
                float w = edge_attr[(size_t)2 * e];
                int pos = atomicAdd(&cnt[dd], 1);
                if (pos < SLOTS) slots[(size_t)dd * SLOTS + pos] = make_int2(s, __float_as_int(w));
            }
        }
        return;
    }

    // ---------------- gemm role: 32 rows ----------------
    int rowBase = (blockIdx.x - scatB) * 32;

    #pragma unroll
    for (int i = 0; i < 8; ++i) {
        int f = tid + i * 256;              // float4 index over W1 (2048)
        *(float4*)&wl[f * 4] = *(const float4*)&W1[f * 4];
    }
    #pragma unroll
    for (int i = 0; i < 4; ++i) {
        int f = tid + i * 256;              // float4 index over 32x128
        int r = f >> 5, q = f & 31;
        if (rowBase + r < N)
            *(float4*)&xs[r * XS_STR + q * 4] = *(const float4*)&x[(size_t)(rowBase + r) * F_IN + q * 4];
    }
    __syncthreads();

    int tr = tid & 15;
    int tc = tid >> 4;

    float4 acc0 = {0,0,0,0}, acc1 = {0,0,0,0};
    #pragma unroll 2
    for (int k = 0; k < F_IN; k += 4) {
        float4 a0 = *(const float4*)&xs[(tr     ) * XS_STR + k];
        float4 a1 = *(const float4*)&xs[(tr + 16) * XS_STR + k];
        float4 w0 = *(const float4*)&wl[(k    ) * HID + tc * 4];
        float4 w1 = *(const float4*)&wl[(k + 1) * HID + tc * 4];
        float4 w2 = *(const float4*)&wl[(k + 2) * HID + tc * 4];
        float4 w3 = *(const float4*)&wl[(k + 3) * HID + tc * 4];
        acc0.x += a0.x*w0.x + a0.y*w1.x + a0.z*w2.x + a0.w*w3.x;
        acc0.y += a0.x*w0.y + a0.y*w1.y + a0.z*w2.y + a0.w*w3.y;
        acc0.z += a0.x*w0.z + a0.y*w1.z + a0.z*w2.z + a0.w*w3.z;
        acc0.w += a0.x*w0.w + a0.y*w1.w + a0.z*w2.w + a0.w*w3.w;
        acc1.x += a1.x*w0.x + a1.y*w1.x + a1.z*w2.x + a1.w*w3.x;
        acc1.y += a1.x*w0.y + a1.y*w1.y + a1.z*w2.y + a1.w*w3.y;
        acc1.z += a1.x*w0.z + a1.y*w1.z + a1.z*w2.z + a1.w*w3.z;
        acc1.w += a1.x*w0.w + a1.y*w1.w + a1.z*w2.w + a1.w*w3.w;
    }

    int row0 = rowBase + tr;
    if (row0      < N) *(float4*)&xw[(size_t)(row0     ) * HID + tc * 4] = acc0;
    if (row0 + 16 < N) *(float4*)&xw[(size_t)(row0 + 16) * HID + tc * 4] = acc1;
}

// ---------------- dinv[d] = rsqrt(sum_w(slots[d]) + 1), wave per node ----------------
__global__ __launch_bounds__(256) void dinv_kernel(const int2* __restrict__ slots,
                                                   const int* __restrict__ cnt,
                                                   float* __restrict__ dinv, int N) {
    int d = blockIdx.x * 4 + (threadIdx.x >> 6);
    if (d >= N) return;
    int lane = threadIdx.x & 63;
    int c = cnt[d]; if (c > SLOTS) c = SLOTS;
    float w = (lane < c) ? __int_as_float(slots[(size_t)d * SLOTS + lane].y) : 0.0f;
    #pragma unroll
    for (int m = 32; m >= 1; m >>= 1)
        w += __shfl_xor(w, m, 64);
    if (lane == 0) dinv[d] = rsqrtf(w + 1.0f);
}

// ---------------- conv1 gather (fused: agg + self + bias + leaky + @W2 reduce) ----------------
// readlane-broadcast: edge src/norm go to SGPRs; xw row loads use scalar base.
__global__ __launch_bounds__(256) void gather1_kernel(const int2* __restrict__ slots,
                                                      const int* __restrict__ cnt,
                                                      const float* __restrict__ dinv,
                                                      const float* __restrict__ xw,
                                                      const float* __restrict__ b1,
                                                      const float* __restrict__ W2,
                                                      float* __restrict__ hw, int N) {
    int d = blockIdx.x * 4 + (threadIdx.x >> 6);
    if (d >= N) return;
    int lane = threadIdx.x & 63;
    int c = cnt[d]; if (c > SLOTS) c = SLOTS;

    int sidx = 0;
    int nbits = 0;
    if (lane < c) {
        int2 sw = slots[(size_t)d * SLOTS + lane];
        sidx  = sw.x;
        nbits = __float_as_int(dinv[sw.x] * __int_as_float(sw.y));
    }
    float di   = dinv[d];
    float self = xw[(size_t)d * HID + lane];

    float acc0 = 0.0f, acc1 = 0.0f, acc2 = 0.0f, acc3 = 0.0f;
    int i = 0;
    for (; i + 7 < c; i += 8) {
        int s0 = __builtin_amdgcn_readlane(sidx, i + 0);
        int s1 = __builtin_amdgcn_readlane(sidx, i + 1);
        int s2 = __builtin_amdgcn_readlane(sidx, i + 2);
        int s3 = __builtin_amdgcn_readlane(sidx, i + 3);
        int s4 = __builtin_amdgcn_readlane(sidx, i + 4);
        int s5 = __builtin_amdgcn_readlane(sidx, i + 5);
        int s6 = __builtin_amdgcn_readlane(sidx, i + 6);
        int s7 = __builtin_amdgcn_readlane(sidx, i + 7);
        float n0 = __int_as_float(__builtin_amdgcn_readlane(nbits, i + 0));
        float n1 = __int_as_float(__builtin_amdgcn_readlane(nbits, i + 1));
        float n2 = __int_as_float(__builtin_amdgcn_readlane(nbits, i + 2));
        float n3 = __int_as_float(__builtin_amdgcn_readlane(nbits, i + 3));
        float n4 = __int_as_float(__builtin_amdgcn_readlane(nbits, i + 4));
        float n5 = __int_as_float(__builtin_amdgcn_readlane(nbits, i + 5));
        float n6 = __int_as_float(__builtin_amdgcn_readlane(nbits, i + 6));
        float n7 = __int_as_float(__builtin_amdgcn_readlane(nbits, i + 7));
        float v0 = (xw + (size_t)s0 * HID)[lane];
        float v1 = (xw + (size_t)s1 * HID)[lane];
        float v2 = (xw + (size_t)s2 * HID)[lane];
        float v3 = (xw + (size_t)s3 * HID)[lane];
        float v4 = (xw + (size_t)s4 * HID)[lane];
        float v5 = (xw + (size_t)s5 * HID)[lane];
        float v6 = (xw + (size_t)s6 * HID)[lane];
        float v7 = (xw + (size_t)s7 * HID)[lane];
        acc0 += v0 * n0; acc1 += v1 * n1; acc2 += v2 * n2; acc3 += v3 * n3;
        acc0 += v4 * n4; acc1 += v5 * n5; acc2 += v6 * n6; acc3 += v7 * n7;
    }
    for (; i < c; ++i) {
        int s   = __builtin_amdgcn_readlane(sidx, i);
        float n = __int_as_float(__builtin_amdgcn_readlane(nbits, i));
        acc0 += (xw + (size_t)s * HID)[lane] * n;
    }
    float acc = (acc0 + acc1) + (acc2 + acc3);

    float v = acc * di + self * di * di + b1[lane];
    v = (v >= 0.0f) ? v : SLOPE * v;
    float p = v * W2[lane];
    #pragma unroll
    for (int m = 32; m >= 1; m >>= 1)
        p += __shfl_xor(p, m, 64);
    if (lane == 0) hw[d] = p;
}

// ---------------- conv2 gather (fused h2): one wave per dst node, lane = edge slot ----------------
__global__ __launch_bounds__(256) void gather2_kernel(const int2* __restrict__ slots,
                                                      const int* __restrict__ cnt,
                                                      const float* __restrict__ dinv,
                                                      const float* __restrict__ hw,
                                                      const float* __restrict__ b2,
                                                      float* __restrict__ h2, int N) {
    int d = blockIdx.x * 4 + (threadIdx.x >> 6);
    if (d >= N) return;
    int lane = threadIdx.x & 63;
    int c = cnt[d]; if (c > SLOTS) c = SLOTS;
    float p = 0.0f;
    if (lane < c) {
        int2 sw = slots[(size_t)d * SLOTS + lane];
        int s = sw.x;
        float w = __int_as_float(sw.y);
        p = hw[s] * dinv[s] * w;
    }
    #pragma unroll
    for (int m = 32; m >= 1; m >>= 1)
        p += __shfl_xor(p, m, 64);
    if (lane == 0) {
        float di = dinv[d];
        float v = p * di + hw[d] * di * di + b2[0];
        h2[d] = (v >= 0.0f) ? v : SLOPE * v;
    }
}

// ---------------- FC1 split-K partial + last-block finalize (fc2 + softmax) ----------------
#define ROWS_PB 16
__global__ __launch_bounds__(128) void fcpart_kernel(const float* __restrict__ h2,
                                                     const float* __restrict__ fc1_W,
                                                     float* __restrict__ fc1_out,
                                                     int* __restrict__ ticket,
                                                     const float* __restrict__ fc1_b,
                                                     const float* __restrict__ fc2_W,
                                                     const float* __restrict__ fc2_b,
                                                     float* __restrict__ out,
                                                     int nodesPerG) {
    int j = threadIdx.x;
    int row0 = blockIdx.x * ROWS_PB;
    __shared__ float hs[NGR][ROWS_PB];
    for (int idx = threadIdx.x; idx < NGR * ROWS_PB; idx += 128) {
        int g = idx / ROWS_PB, r = idx % ROWS_PB;
        hs[g][r] = h2[(size_t)g * nodesPerG + row0 + r];
    }
    __syncthreads();
    float acc[NGR];
    #pragma unroll
    for (int g = 0; g < NGR; ++g) acc[g] = 0.0f;
    #pragma unroll
    for (int r = 0; r < ROWS_PB; ++r) {
        float wv = fc1_W[(size_t)(row0 + r) * FC_HID + j];
        #pragma unroll
        for (int g = 0; g < NGR; ++g) acc[g] += hs[g][r] * wv;
    }
    #pragma unroll
    for (int g = 0; g < NGR; ++g) atomicAdd(&fc1_out[g * FC_HID + j], acc[g]);

    __threadfence();
    __shared__ int lastFlag;
    if (j == 0) lastFlag = (atomicAdd(ticket, 1) == (int)gridDim.x - 1);
    __syncthreads();
    if (!lastFlag) return;
    __threadfence();

    __shared__ float hid[NGR][FC_HID];
    __shared__ float outs[NGR * NOUT];
    #pragma unroll
    for (int g = 0; g < NGR; ++g) {
        float v = atomicAdd(&fc1_out[g * FC_HID + j], 0.0f) + fc1_b[j];  // coherent load
        hid[g][j] = (v >= 0.0f) ? v : SLOPE * v;
    }
    __syncthreads();
    if (j < NGR * NOUT) {
        int g = j >> 1, o = j & 1;
        float a = fc2_b[o];
        #pragma unroll
        for (int k = 0; k < FC_HID; ++k)
            a += hid[g][k] * fc2_W[(size_t)k * NOUT + o];
        outs[j] = a;
    }
    __syncthreads();
    if (j < NGR) {
        float o0 = outs[j * 2], o1 = outs[j * 2 + 1];
        float m = fmaxf(o0, o1);
        float e0 = __expf(o0 - m), e1 = __expf(o1 - m);
        float s = e0 + e1;
        out[(size_t)j * NOUT + 0] = e0 / s;
        out[(size_t)j * NOUT + 1] = e1 / s;
    }
}

extern "C" void kernel_launch(void* const* d_in, const int* in_sizes, int n_in,
                              void* d_out, int out_size, void* d_ws, size_t ws_size,
                              hipStream_t stream) {
    const float* x          = (const float*)d_in[0];
    const int*   edge_index = (const int*)d_in[1];
    const float* edge_attr  = (const float*)d_in[2];
    const float* W1         = (const float*)d_in[3];
    const float* b1         = (const float*)d_in[4];
    const float* W2         = (const float*)d_in[5];
    const float* b2         = (const float*)d_in[6];
    const float* fc1_W      = (const float*)d_in[7];
    const float* fc1_b      = (const float*)d_in[8];
    const float* fc2_W      = (const float*)d_in[9];
    const float* fc2_b      = (const float*)d_in[10];
    float* out = (float*)d_out;

    int N = in_sizes[0] / F_IN;
    int E = in_sizes[1] / 2;
    int nodesPerG = in_sizes[7] / FC_HID;

    const int* src = edge_index;
    const int* dst = edge_index + E;

    // workspace layout: zeroed region first (cnt + fc1out + ticket)
    char* wsb = (char*)d_ws;
    int*   cnt    = (int*)wsb;                                   // N ints
    float* fc1out = (float*)(wsb + (size_t)N * 4);               // NGR*FC_HID floats
    int*   ticket = (int*)(wsb + (size_t)N * 4 + NGR * FC_HID * 4);  // 1 int (pad to 16)
    size_t zeroBytes = (size_t)N * 4 + (size_t)NGR * FC_HID * 4 + 16;
    int2*  slots  = (int2*)(wsb + zeroBytes);                    // N*SLOTS int2 (16 MB)
    float* xw     = (float*)(wsb + zeroBytes + (size_t)N * SLOTS * 8);  // N*HID
    float* dinv   = xw + (size_t)N * HID;                        // N
    float* hw     = dinv + N;                                    // N
    float* h2     = hw + N;                                      // N

    int n4 = (int)(zeroBytes / 16);
    zero_kernel<<<(n4 + 255) / 256, 256, 0, stream>>>((int4*)d_ws, n4);

    int scatB = (E + EPT * 256 - 1) / (EPT * 256);
    int gemmB = (N + 31) / 32;
    fused_sg_kernel<<<scatB + gemmB, 256, 0, stream>>>(src, dst, edge_attr, cnt, slots, E,
                                                       x, W1, xw, N, scatB);
    dinv_kernel<<<(N + 3) / 4, 256, 0, stream>>>(slots, cnt, dinv, N);
    gather1_kernel<<<(N + 3) / 4, 256, 0, stream>>>(slots, cnt, dinv, xw, b1, W2, hw, N);
    gather2_kernel<<<(N + 3) / 4, 256, 0, stream>>>(slots, cnt, dinv, hw, b2, h2, N);
    fcpart_kernel<<<nodesPerG / ROWS_PB, 128, 0, stream>>>(h2, fc1_W, fc1out, ticket,
                                                           fc1_b, fc2_W, fc2_b, out, nodesPerG);
}